// Round 4
// baseline (1072.638 us; speedup 1.0000x reference)
//
#include <hip/hip_runtime.h>
#include <hip/hip_fp16.h>

// Problem constants
#define BB 4
#define TT 16
#define HH 512
#define WW 512

// Tile: 256 threads, output 128 wide x 64 tall; thread = 8 wide x 4 tall (16 tx x 16 ty)
#define TW 128
#define TH 64
#define SRODS 80              // staged rows (64 + 2*8 halo)
#define ROW_BYTES 320         // 20 quads of 16B; 18 used (144 px fp16), 2 pad
#define PLANE_BYTES (SRODS * ROW_BYTES)   // 25600

// Merged tap table: union of dil-1,2,4 5x5 grids = 57 offsets (vs 75).
// Rows in the union and their column sets:
__device__ __constant__ const int kROFF[9] = {-8, -4, -2, -1, 0, 1, 2, 4, 8};
#define RC0 5
#define RC1 7
#define RC2 7
#define RC3 5
#define RC4 9
#define RC5 5
#define RC6 7
#define RC7 7
#define RC8 5

__device__ const int kRCNT[9]  = {RC0, RC1, RC2, RC3, RC4, RC5, RC6, RC7, RC8};
__device__ const int kRBASE[9] = {0, 5, 12, 19, 24, 33, 38, 45, 52};
__device__ const int kCOLS[57] = {
    -8, -4,  0,  4,  8,                  // r = -8
    -8, -4, -2,  0,  2,  4,  8,          // r = -4
    -4, -2, -1,  0,  1,  2,  4,          // r = -2
    -2, -1,  0,  1,  2,                  // r = -1
    -8, -4, -2, -1,  0,  1,  2,  4,  8,  // r =  0
    -2, -1,  0,  1,  2,                  // r =  1
    -4, -2, -1,  0,  1,  2,  4,          // r =  2
    -8, -4, -2,  0,  2,  4,  8,          // r =  4
    -8, -4,  0,  4,  8                   // r =  8
};

__device__ __forceinline__ int reflect_idx(int q, int n) {
    q = abs(q);
    if (q >= n) q = 2 * n - 2 - q;
    return q;
}

// pw[ch*57 + e] = sum over branches b (dil d=1,2,4) of s_b * w_b[ch][r/d+2][c/d+2]
// where (r,c) = merged tap e and d divides both. pw[171] = combined bias.
__global__ void pack_weights(const float* __restrict__ w1, const float* __restrict__ b1,
                             const float* __restrict__ w2, const float* __restrict__ b2,
                             const float* __restrict__ w3, const float* __restrict__ b3,
                             const float* __restrict__ sa, const float* __restrict__ sb,
                             const float* __restrict__ sc, float* __restrict__ pw) {
    int tid = threadIdx.x;
    float s[3] = {sa[0], sb[0], sc[0]};
    const float* wp[3] = {w1, w2, w3};
    if (tid < 171) {
        int ch = tid / 57;
        int e  = tid % 57;
        int ri = 8;
        for (int k = 8; k >= 0; --k)
            if (e < kRBASE[k] + kRCNT[k]) ri = k;
        int r = kROFF[ri];
        int c = kCOLS[e];
        float acc = 0.0f;
        for (int b = 0; b < 3; ++b) {
            int d = 1 << b;
            if (r % d == 0 && c % d == 0) {
                int rd = r / d, cd = c / d;
                if (rd >= -2 && rd <= 2 && cd >= -2 && cd <= 2)
                    acc += s[b] * wp[b][ch * 25 + (rd + 2) * 5 + (cd + 2)];
            }
        }
        pw[tid] = acc;
    }
    if (tid == 0) pw[171] = s[0] * b1[0] + s[1] * b2[0] + s[2] * b3[0];
}

__global__ __launch_bounds__(256, 6) void conv_block(const float* __restrict__ x,
                                                     float* __restrict__ out,
                                                     const float* __restrict__ pw) {
    __shared__ char lds[PLANE_BYTES];   // one fp16 channel plane, 25.6 KB -> 6 blocks/CU

    const int bt = blockIdx.z;
    const int t  = bt % TT;
    const int h0 = blockIdx.y * TH;
    const int w0 = blockIdx.x * TW;
    const int tid = threadIdx.x;
    const int tx = tid & 15;
    const int ty = tid >> 4;
    const int oc = tx * 8;
    const int orow = ty * 4;

    const int tprev = (t == 0) ? 1 : t - 1;
    const int tnext = (t == TT - 1) ? TT - 2 : t + 1;
    const int bbase = (bt / TT) * TT;
    const size_t fs = (size_t)HH * WW;
    const float* frp = x + (size_t)(bbase + tprev) * fs;
    const float* frc = x + (size_t)bt * fs;
    const float* frn = x + (size_t)(bbase + tnext) * fs;

    const float bias = pw[171];
    float acc[4][8];
#pragma unroll
    for (int p = 0; p < 4; ++p)
#pragma unroll
        for (int q = 0; q < 8; ++q) acc[p][q] = bias;

#pragma unroll 1
    for (int ch = 0; ch < 3; ++ch) {
        const float* src = (ch == 0) ? frp : (ch == 1) ? frc : frn;

        __syncthreads();   // protect plane from previous channel's readers
        // ---- Stage one channel plane: fp32 global -> fp16 LDS, quad-XOR by (row>>2)&1 ----
        for (int k = tid; k < SRODS * 18; k += 256) {
            int row = k / 18;
            int c8  = k - row * 18;
            int gh = reflect_idx(h0 - 8 + row, HH);
            int gb = w0 - 8 + c8 * 8;
            const float* rsrc = src + (size_t)gh * WW;
            float4 v0, v1;
            if (gb >= 0 && gb + 7 < WW) {
                v0 = *reinterpret_cast<const float4*>(rsrc + gb);
                v1 = *reinterpret_cast<const float4*>(rsrc + gb + 4);
            } else {
                v0 = make_float4(rsrc[reflect_idx(gb + 0, WW)], rsrc[reflect_idx(gb + 1, WW)],
                                 rsrc[reflect_idx(gb + 2, WW)], rsrc[reflect_idx(gb + 3, WW)]);
                v1 = make_float4(rsrc[reflect_idx(gb + 4, WW)], rsrc[reflect_idx(gb + 5, WW)],
                                 rsrc[reflect_idx(gb + 6, WW)], rsrc[reflect_idx(gb + 7, WW)]);
            }
            union { __half2 h[4]; uint4 u; } cv;
            cv.h[0] = __floats2half2_rn(v0.x, v0.y);
            cv.h[1] = __floats2half2_rn(v0.z, v0.w);
            cv.h[2] = __floats2half2_rn(v1.x, v1.y);
            cv.h[3] = __floats2half2_rn(v1.z, v1.w);
            int pq = c8 ^ ((row >> 2) & 1);
            *reinterpret_cast<uint4*>(lds + row * ROW_BYTES + pq * 16) = cv.u;
        }
        __syncthreads();

        const float* wc = pw + ch * 57;   // uniform -> scalar loads

        // ---- Compute: per output row p, read the 9 needed tap rows, 57 taps each ----
#pragma unroll
        for (int p = 0; p < 4; ++p) {
#pragma unroll
            for (int ri = 0; ri < 9; ++ri) {
                const int row = orow + p + 8 + kROFF[ri];
                const int xb = (row >> 2) & 1;
                const char* rp = lds + row * ROW_BYTES;
                union { uint4 u[3]; __half h[24]; } R;
                R.u[0] = *reinterpret_cast<const uint4*>(rp + (((tx + 0) ^ xb) << 4));
                R.u[1] = *reinterpret_cast<const uint4*>(rp + (((tx + 1) ^ xb) << 4));
                R.u[2] = *reinterpret_cast<const uint4*>(rp + (((tx + 2) ^ xb) << 4));
#pragma unroll
                for (int ci = 0; ci < kRCNT[ri]; ++ci) {
                    const float wv = wc[kRBASE[ri] + ci];
                    const int c = kCOLS[kRBASE[ri] + ci];
#pragma unroll
                    for (int q = 0; q < 8; ++q)
                        acc[p][q] = fmaf(wv, __half2float(R.h[q + 8 + c]), acc[p][q]);
                }
            }
        }
    }

    // ---- Epilogue: tanh + fp32 store ----
    float* dst = out + (size_t)bt * fs + (size_t)h0 * WW + w0;
#pragma unroll
    for (int p = 0; p < 4; ++p) {
#pragma unroll
        for (int q = 0; q < 8; ++q) {
            float v = acc[p][q];
            float e = __expf(2.0f * v);
            acc[p][q] = 1.0f - 2.0f / (e + 1.0f);
        }
        float4 v0 = make_float4(acc[p][0], acc[p][1], acc[p][2], acc[p][3]);
        float4 v1 = make_float4(acc[p][4], acc[p][5], acc[p][6], acc[p][7]);
        float* rowp = dst + (size_t)(orow + p) * WW + oc;
        *reinterpret_cast<float4*>(rowp) = v0;
        *reinterpret_cast<float4*>(rowp + 4) = v1;
    }
}

extern "C" void kernel_launch(void* const* d_in, const int* in_sizes, int n_in,
                              void* d_out, int out_size, void* d_ws, size_t ws_size,
                              hipStream_t stream) {
    const float* x = (const float*)d_in[0];
    float* pw1 = (float*)d_ws;
    float* pw2 = (float*)d_ws + 256;
    float* y   = (float*)((char*)d_ws + 4096);   // intermediate, 64 MB
    float* z   = (float*)d_out;

    pack_weights<<<1, 256, 0, stream>>>((const float*)d_in[1], (const float*)d_in[2],
                                        (const float*)d_in[3], (const float*)d_in[4],
                                        (const float*)d_in[5], (const float*)d_in[6],
                                        (const float*)d_in[7], (const float*)d_in[8],
                                        (const float*)d_in[9], pw1);
    pack_weights<<<1, 256, 0, stream>>>((const float*)d_in[10], (const float*)d_in[11],
                                        (const float*)d_in[12], (const float*)d_in[13],
                                        (const float*)d_in[14], (const float*)d_in[15],
                                        (const float*)d_in[16], (const float*)d_in[17],
                                        (const float*)d_in[18], pw2);

    dim3 grid(WW / TW, HH / TH, BB * TT);
    conv_block<<<grid, 256, 0, stream>>>(x, y, pw1);
    conv_block<<<grid, 256, 0, stream>>>(y, z, pw2);
}

// Round 5
// 390.668 us; speedup vs baseline: 2.7456x; 2.7456x over previous
//
#include <hip/hip_runtime.h>
#include <hip/hip_fp16.h>

// Problem constants
#define BB 4
#define TT 16
#define HH 512
#define WW 512

// Tile: 256 threads, output 128 wide x 64 tall; thread = 8 wide x 4 tall (16 tx x 16 ty)
#define TW 128
#define TH 64
#define SRODS 80              // staged rows (64 + 2*8 halo)
#define ROW_BYTES 320         // 20 quads of 16B; 18 used (144 px fp16), 2 pad
#define PLANE_BYTES (SRODS * ROW_BYTES)   // 25600 B -> 5-6 blocks/CU

// Merged tap table: union of dil-1,2,4 5x5 grids = 57 offsets (vs 75 separate).
// COMPILE-TIME constants (constexpr, not __device__ memory!) so that after
// full unroll every index below folds to a literal -> no scratch (round-4 bug).
constexpr int kTapR[57] = {
    -8, -8, -8, -8, -8,
    -4, -4, -4, -4, -4, -4, -4,
    -2, -2, -2, -2, -2, -2, -2,
    -1, -1, -1, -1, -1,
     0,  0,  0,  0,  0,  0,  0,  0,  0,
     1,  1,  1,  1,  1,
     2,  2,  2,  2,  2,  2,  2,
     4,  4,  4,  4,  4,  4,  4,
     8,  8,  8,  8,  8};
constexpr int kTapC[57] = {
    -8, -4,  0,  4,  8,
    -8, -4, -2,  0,  2,  4,  8,
    -4, -2, -1,  0,  1,  2,  4,
    -2, -1,  0,  1,  2,
    -8, -4, -2, -1,  0,  1,  2,  4,  8,
    -2, -1,  0,  1,  2,
    -4, -2, -1,  0,  1,  2,  4,
    -8, -4, -2,  0,  2,  4,  8,
    -8, -4,  0,  4,  8};

__device__ __forceinline__ int reflect_idx(int q, int n) {
    q = abs(q);
    if (q >= n) q = 2 * n - 2 - q;
    return q;
}

// pw[ch*57 + e] = sum over branches b (dil d=1,2,4) that hit merged tap e of
//                 s_b * w_b[ch][r/d+2][c/d+2].   pw[171] = combined bias.
__global__ void pack_weights(const float* __restrict__ w1, const float* __restrict__ b1,
                             const float* __restrict__ w2, const float* __restrict__ b2,
                             const float* __restrict__ w3, const float* __restrict__ b3,
                             const float* __restrict__ sa, const float* __restrict__ sb,
                             const float* __restrict__ sc, float* __restrict__ pw) {
    int tid = threadIdx.x;
    float s[3] = {sa[0], sb[0], sc[0]};
    const float* wp[3] = {w1, w2, w3};
    if (tid < 171) {
        int ch = tid / 57;
        int e  = tid % 57;
        int r = kTapR[e];
        int c = kTapC[e];
        float acc = 0.0f;
        for (int b = 0; b < 3; ++b) {
            int d = 1 << b;
            if (r % d == 0 && c % d == 0) {
                int rd = r / d, cd = c / d;
                if (rd >= -2 && rd <= 2 && cd >= -2 && cd <= 2)
                    acc += s[b] * wp[b][ch * 25 + (rd + 2) * 5 + (cd + 2)];
            }
        }
        pw[tid] = acc;
    }
    if (tid == 0) pw[171] = s[0] * b1[0] + s[1] * b2[0] + s[2] * b3[0];
}

__global__ __launch_bounds__(256, 5) void conv_block(const float* __restrict__ x,
                                                     float* __restrict__ out,
                                                     const float* __restrict__ pw) {
    __shared__ char lds[PLANE_BYTES];   // one fp16 channel plane at a time

    const int bt = blockIdx.z;
    const int t  = bt % TT;
    const int h0 = blockIdx.y * TH;
    const int w0 = blockIdx.x * TW;
    const int tid = threadIdx.x;
    const int tx = tid & 15;
    const int ty = tid >> 4;
    const int oc = tx * 8;
    const int orow = ty * 4;

    const int tprev = (t == 0) ? 1 : t - 1;
    const int tnext = (t == TT - 1) ? TT - 2 : t + 1;
    const int bbase = (bt / TT) * TT;
    const size_t fs = (size_t)HH * WW;
    const float* frp = x + (size_t)(bbase + tprev) * fs;
    const float* frc = x + (size_t)bt * fs;
    const float* frn = x + (size_t)(bbase + tnext) * fs;

    const float bias = pw[171];
    float acc[4][8];
#pragma unroll
    for (int p = 0; p < 4; ++p)
#pragma unroll
        for (int q = 0; q < 8; ++q) acc[p][q] = bias;

#pragma unroll 1
    for (int ch = 0; ch < 3; ++ch) {
        const float* src = (ch == 0) ? frp : (ch == 1) ? frc : frn;

        __syncthreads();   // protect plane from previous channel's readers
        // ---- Stage one channel plane: fp32 global -> fp16 LDS, quad-XOR by (row>>2)&1 ----
        for (int k = tid; k < SRODS * 18; k += 256) {
            int row = k / 18;
            int c8  = k - row * 18;
            int gh = reflect_idx(h0 - 8 + row, HH);
            int gb = w0 - 8 + c8 * 8;
            const float* rsrc = src + (size_t)gh * WW;
            float4 v0, v1;
            if (gb >= 0 && gb + 7 < WW) {
                v0 = *reinterpret_cast<const float4*>(rsrc + gb);
                v1 = *reinterpret_cast<const float4*>(rsrc + gb + 4);
            } else {
                v0 = make_float4(rsrc[reflect_idx(gb + 0, WW)], rsrc[reflect_idx(gb + 1, WW)],
                                 rsrc[reflect_idx(gb + 2, WW)], rsrc[reflect_idx(gb + 3, WW)]);
                v1 = make_float4(rsrc[reflect_idx(gb + 4, WW)], rsrc[reflect_idx(gb + 5, WW)],
                                 rsrc[reflect_idx(gb + 6, WW)], rsrc[reflect_idx(gb + 7, WW)]);
            }
            union { __half2 h[4]; uint4 u; } cv;
            cv.h[0] = __floats2half2_rn(v0.x, v0.y);
            cv.h[1] = __floats2half2_rn(v0.z, v0.w);
            cv.h[2] = __floats2half2_rn(v1.x, v1.y);
            cv.h[3] = __floats2half2_rn(v1.z, v1.w);
            int pq = c8 ^ ((row >> 2) & 1);
            *reinterpret_cast<uint4*>(lds + row * ROW_BYTES + pq * 16) = cv.u;
        }
        __syncthreads();

        const float* wc = pw + ch * 57;   // uniform -> scalar loads

        // ---- Row-streaming: read each of the 20 needed rows ONCE, apply all taps ----
#pragma unroll
        for (int rr = 0; rr < 20; ++rr) {
            const int row = orow + rr;
            const int xb = (row >> 2) & 1;
            const char* rp = lds + row * ROW_BYTES;
            union { uint4 u[3]; __half h[24]; } R;
            R.u[0] = *reinterpret_cast<const uint4*>(rp + (((tx + 0) ^ xb) << 4));
            R.u[1] = *reinterpret_cast<const uint4*>(rp + (((tx + 1) ^ xb) << 4));
            R.u[2] = *reinterpret_cast<const uint4*>(rp + (((tx + 2) ^ xb) << 4));
#pragma unroll
            for (int e = 0; e < 57; ++e) {
                const int pr = rr - 8 - kTapR[e];     // literal after unroll
                if (pr < 0 || pr > 3) continue;       // compile-time fold
                const float wv = wc[e];
                const int cb = 8 + kTapC[e];
#pragma unroll
                for (int q = 0; q < 8; ++q)
                    acc[pr][q] = fmaf(wv, __half2float(R.h[cb + q]), acc[pr][q]);
            }
        }
    }

    // ---- Epilogue: tanh + fp32 store ----
    float* dst = out + (size_t)bt * fs + (size_t)h0 * WW + w0;
#pragma unroll
    for (int p = 0; p < 4; ++p) {
#pragma unroll
        for (int q = 0; q < 8; ++q) {
            float v = acc[p][q];
            float e = __expf(2.0f * v);
            acc[p][q] = 1.0f - 2.0f / (e + 1.0f);
        }
        float4 v0 = make_float4(acc[p][0], acc[p][1], acc[p][2], acc[p][3]);
        float4 v1 = make_float4(acc[p][4], acc[p][5], acc[p][6], acc[p][7]);
        float* rowp = dst + (size_t)(orow + p) * WW + oc;
        *reinterpret_cast<float4*>(rowp) = v0;
        *reinterpret_cast<float4*>(rowp + 4) = v1;
    }
}

extern "C" void kernel_launch(void* const* d_in, const int* in_sizes, int n_in,
                              void* d_out, int out_size, void* d_ws, size_t ws_size,
                              hipStream_t stream) {
    const float* x = (const float*)d_in[0];
    float* pw1 = (float*)d_ws;
    float* pw2 = (float*)d_ws + 256;
    float* y   = (float*)((char*)d_ws + 4096);   // intermediate, 64 MB
    float* z   = (float*)d_out;

    pack_weights<<<1, 256, 0, stream>>>((const float*)d_in[1], (const float*)d_in[2],
                                        (const float*)d_in[3], (const float*)d_in[4],
                                        (const float*)d_in[5], (const float*)d_in[6],
                                        (const float*)d_in[7], (const float*)d_in[8],
                                        (const float*)d_in[9], pw1);
    pack_weights<<<1, 256, 0, stream>>>((const float*)d_in[10], (const float*)d_in[11],
                                        (const float*)d_in[12], (const float*)d_in[13],
                                        (const float*)d_in[14], (const float*)d_in[15],
                                        (const float*)d_in[16], (const float*)d_in[17],
                                        (const float*)d_in[18], pw2);

    dim3 grid(WW / TW, HH / TH, BB * TT);
    conv_block<<<grid, 256, 0, stream>>>(x, y, pw1);
    conv_block<<<grid, 256, 0, stream>>>(y, z, pw2);
}

// Round 6
// 296.280 us; speedup vs baseline: 3.6204x; 1.3186x over previous
//
#include <hip/hip_runtime.h>
#include <hip/hip_fp16.h>

// Problem constants
#define BB 4
#define TT 16
#define HH 512
#define WW 512

// Tile: 256 threads, output 128 wide x 64 tall; thread = 8 wide x 4 tall (16 tx x 16 ty)
#define TW 128
#define TH 64
#define SRODS 80              // staged rows (64 + 2*8 halo)
#define ROW_BYTES 336         // 84 dwords (mod 32 == 20): rows 4 apart offset by 16 dwords
#define PLANE_BYTES (SRODS * ROW_BYTES)   // 26880 B

// Merged tap table: union of dil-1,2,4 5x5 grids = 57 offsets (vs 75 separate).
constexpr int kTapR[57] = {
    -8, -8, -8, -8, -8,
    -4, -4, -4, -4, -4, -4, -4,
    -2, -2, -2, -2, -2, -2, -2,
    -1, -1, -1, -1, -1,
     0,  0,  0,  0,  0,  0,  0,  0,  0,
     1,  1,  1,  1,  1,
     2,  2,  2,  2,  2,  2,  2,
     4,  4,  4,  4,  4,  4,  4,
     8,  8,  8,  8,  8};
constexpr int kTapC[57] = {
    -8, -4,  0,  4,  8,
    -8, -4, -2,  0,  2,  4,  8,
    -4, -2, -1,  0,  1,  2,  4,
    -2, -1,  0,  1,  2,
    -8, -4, -2, -1,  0,  1,  2,  4,  8,
    -2, -1,  0,  1,  2,
    -4, -2, -1,  0,  1,  2,  4,
    -8, -4, -2,  0,  2,  4,  8,
    -8, -4,  0,  4,  8};

__device__ __forceinline__ int reflect_idx(int q, int n) {
    q = abs(q);
    if (q >= n) q = 2 * n - 2 - q;
    return q;
}

// ---- Template-recursive tap application: ALL indices compile-time by construction ----
template <int E, int RR>
__device__ __forceinline__ void taps(const float* __restrict__ wc,
                                     const __half (&Rh)[24], float (&acc)[4][8]) {
    if constexpr (E < 57) {
        constexpr int pr = RR - 8 - kTapR[E];      // output row this tap row feeds
        if constexpr (pr >= 0 && pr <= 3) {
            const float wv = wc[E];                // uniform scalar load, literal offset
            constexpr int cb = 8 + kTapC[E];
#pragma unroll
            for (int q = 0; q < 8; ++q)
                acc[pr][q] = fmaf(wv, __half2float(Rh[cb + q]), acc[pr][q]);
        }
        taps<E + 1, RR>(wc, Rh, acc);
    }
}

template <int RR>
__device__ __forceinline__ void rows_from(const char* __restrict__ base,
                                          const float* __restrict__ wc, float (&acc)[4][8]) {
    if constexpr (RR < 20) {
        union { uint4 u[3]; __half h[24]; } R;     // literal-indexed union: SROA-safe (r3)
        R.u[0] = *reinterpret_cast<const uint4*>(base + RR * ROW_BYTES + 0);
        R.u[1] = *reinterpret_cast<const uint4*>(base + RR * ROW_BYTES + 16);
        R.u[2] = *reinterpret_cast<const uint4*>(base + RR * ROW_BYTES + 32);
        taps<0, RR>(wc, R.h, acc);
        rows_from<RR + 1>(base, wc, acc);
    }
}

// pw[ch*57 + e] = sum over branches b (dil d=1,2,4) hitting merged tap e of
//                 s_b * w_b[ch][r/d+2][c/d+2].   pw[171] = combined bias.
__global__ void pack_weights(const float* __restrict__ w1, const float* __restrict__ b1,
                             const float* __restrict__ w2, const float* __restrict__ b2,
                             const float* __restrict__ w3, const float* __restrict__ b3,
                             const float* __restrict__ sa, const float* __restrict__ sb,
                             const float* __restrict__ sc, float* __restrict__ pw) {
    int tid = threadIdx.x;
    float s[3] = {sa[0], sb[0], sc[0]};
    const float* wp[3] = {w1, w2, w3};
    if (tid < 171) {
        int ch = tid / 57;
        int e  = tid % 57;
        int r = kTapR[e];
        int c = kTapC[e];
        float acc = 0.0f;
        for (int b = 0; b < 3; ++b) {
            int d = 1 << b;
            if (r % d == 0 && c % d == 0) {
                int rd = r / d, cd = c / d;
                if (rd >= -2 && rd <= 2 && cd >= -2 && cd <= 2)
                    acc += s[b] * wp[b][ch * 25 + (rd + 2) * 5 + (cd + 2)];
            }
        }
        pw[tid] = acc;
    }
    if (tid == 0) pw[171] = s[0] * b1[0] + s[1] * b2[0] + s[2] * b3[0];
}

__global__ __launch_bounds__(256, 4) void conv_block(const float* __restrict__ x,
                                                     float* __restrict__ out,
                                                     const float* __restrict__ pw) {
    __shared__ char lds[PLANE_BYTES];   // one fp16 channel plane at a time

    const int bt = blockIdx.z;
    const int t  = bt % TT;
    const int h0 = blockIdx.y * TH;
    const int w0 = blockIdx.x * TW;
    const int tid = threadIdx.x;
    const int tx = tid & 15;
    const int ty = tid >> 4;
    const int oc = tx * 8;
    const int orow = ty * 4;

    const int tprev = (t == 0) ? 1 : t - 1;
    const int tnext = (t == TT - 1) ? TT - 2 : t + 1;
    const int bbase = (bt / TT) * TT;
    const size_t fs = (size_t)HH * WW;
    const float* frp = x + (size_t)(bbase + tprev) * fs;
    const float* frc = x + (size_t)bt * fs;
    const float* frn = x + (size_t)(bbase + tnext) * fs;

    const float bias = pw[171];
    float acc[4][8];
#pragma unroll
    for (int p = 0; p < 4; ++p)
#pragma unroll
        for (int q = 0; q < 8; ++q) acc[p][q] = bias;

#pragma unroll 1
    for (int ch = 0; ch < 3; ++ch) {
        const float* src = (ch == 0) ? frp : (ch == 1) ? frc : frn;

        __syncthreads();   // protect plane from previous channel's readers
        // ---- Stage one channel plane: fp32 global -> fp16 LDS (linear layout) ----
        for (int k = tid; k < SRODS * 18; k += 256) {
            int row = k / 18;
            int c8  = k - row * 18;
            int gh = reflect_idx(h0 - 8 + row, HH);
            int gb = w0 - 8 + c8 * 8;
            const float* rsrc = src + (size_t)gh * WW;
            float4 v0, v1;
            if (gb >= 0 && gb + 7 < WW) {
                v0 = *reinterpret_cast<const float4*>(rsrc + gb);
                v1 = *reinterpret_cast<const float4*>(rsrc + gb + 4);
            } else {
                v0 = make_float4(rsrc[reflect_idx(gb + 0, WW)], rsrc[reflect_idx(gb + 1, WW)],
                                 rsrc[reflect_idx(gb + 2, WW)], rsrc[reflect_idx(gb + 3, WW)]);
                v1 = make_float4(rsrc[reflect_idx(gb + 4, WW)], rsrc[reflect_idx(gb + 5, WW)],
                                 rsrc[reflect_idx(gb + 6, WW)], rsrc[reflect_idx(gb + 7, WW)]);
            }
            union { __half2 h[4]; uint4 u; } cv;
            cv.h[0] = __floats2half2_rn(v0.x, v0.y);
            cv.h[1] = __floats2half2_rn(v0.z, v0.w);
            cv.h[2] = __floats2half2_rn(v1.x, v1.y);
            cv.h[3] = __floats2half2_rn(v1.z, v1.w);
            *reinterpret_cast<uint4*>(lds + row * ROW_BYTES + c8 * 16) = cv.u;
        }
        __syncthreads();

        // ---- Row-streaming: forced-static 20-row x 57-tap expansion ----
        const char* base = lds + orow * ROW_BYTES + tx * 16;
        rows_from<0>(base, pw + ch * 57, acc);
    }

    // ---- Epilogue: tanh + fp32 store ----
    float* dst = out + (size_t)bt * fs + (size_t)h0 * WW + w0;
#pragma unroll
    for (int p = 0; p < 4; ++p) {
#pragma unroll
        for (int q = 0; q < 8; ++q) {
            float v = acc[p][q];
            float e = __expf(2.0f * v);
            acc[p][q] = 1.0f - 2.0f / (e + 1.0f);
        }
        float4 v0 = make_float4(acc[p][0], acc[p][1], acc[p][2], acc[p][3]);
        float4 v1 = make_float4(acc[p][4], acc[p][5], acc[p][6], acc[p][7]);
        float* rowp = dst + (size_t)(orow + p) * WW + oc;
        *reinterpret_cast<float4*>(rowp) = v0;
        *reinterpret_cast<float4*>(rowp + 4) = v1;
    }
}

extern "C" void kernel_launch(void* const* d_in, const int* in_sizes, int n_in,
                              void* d_out, int out_size, void* d_ws, size_t ws_size,
                              hipStream_t stream) {
    const float* x = (const float*)d_in[0];
    float* pw1 = (float*)d_ws;
    float* pw2 = (float*)d_ws + 256;
    float* y   = (float*)((char*)d_ws + 4096);   // intermediate, 64 MB
    float* z   = (float*)d_out;

    pack_weights<<<1, 256, 0, stream>>>((const float*)d_in[1], (const float*)d_in[2],
                                        (const float*)d_in[3], (const float*)d_in[4],
                                        (const float*)d_in[5], (const float*)d_in[6],
                                        (const float*)d_in[7], (const float*)d_in[8],
                                        (const float*)d_in[9], pw1);
    pack_weights<<<1, 256, 0, stream>>>((const float*)d_in[10], (const float*)d_in[11],
                                        (const float*)d_in[12], (const float*)d_in[13],
                                        (const float*)d_in[14], (const float*)d_in[15],
                                        (const float*)d_in[16], (const float*)d_in[17],
                                        (const float*)d_in[18], pw2);

    dim3 grid(WW / TW, HH / TH, BB * TT);
    conv_block<<<grid, 256, 0, stream>>>(x, y, pw1);
    conv_block<<<grid, 256, 0, stream>>>(y, z, pw2);
}

// Round 7
// 295.810 us; speedup vs baseline: 3.6261x; 1.0016x over previous
//
#include <hip/hip_runtime.h>
#include <hip/hip_fp16.h>

// Problem constants
#define BB 4
#define TT 16
#define HH 512
#define WW 512

// Tile: 256 threads, output 128 wide x 64 tall; thread = 8 wide x 4 tall (16 tx x 16 ty)
#define TW 128
#define TH 64
#define SRODS 80              // staged rows (64 + 2*8 halo)
#define ROW_BYTES 288         // 144 halfs exactly (72 dwords); conflicts fixed by quad-XOR
#define PLANE_BYTES (SRODS * ROW_BYTES)   // 23040 B -> 4+ blocks/CU

// Merged tap table: union of dil-1,2,4 5x5 grids = 57 offsets (vs 75 separate).
constexpr int kTapR[57] = {
    -8, -8, -8, -8, -8,
    -4, -4, -4, -4, -4, -4, -4,
    -2, -2, -2, -2, -2, -2, -2,
    -1, -1, -1, -1, -1,
     0,  0,  0,  0,  0,  0,  0,  0,  0,
     1,  1,  1,  1,  1,
     2,  2,  2,  2,  2,  2,  2,
     4,  4,  4,  4,  4,  4,  4,
     8,  8,  8,  8,  8};
constexpr int kTapC[57] = {
    -8, -4,  0,  4,  8,
    -8, -4, -2,  0,  2,  4,  8,
    -4, -2, -1,  0,  1,  2,  4,
    -2, -1,  0,  1,  2,
    -8, -4, -2, -1,  0,  1,  2,  4,  8,
    -2, -1,  0,  1,  2,
    -4, -2, -1,  0,  1,  2,  4,
    -8, -4, -2,  0,  2,  4,  8,
    -8, -4,  0,  4,  8};

__device__ __forceinline__ int reflect_idx(int q, int n) {
    q = abs(q);
    if (q >= n) q = 2 * n - 2 - q;
    return q;
}

// ---- Template-recursive tap application: ALL indices compile-time by construction ----
template <int E, int RR>
__device__ __forceinline__ void taps(const float* __restrict__ wc,
                                     const float (&rf)[24], float (&acc)[4][8]) {
    if constexpr (E < 57) {
        constexpr int pr = RR - 8 - kTapR[E];      // output row this tap row feeds
        if constexpr (pr >= 0 && pr <= 3) {
            const float wv = wc[E];                // uniform scalar load, literal offset
            constexpr int cb = 8 + kTapC[E];
#pragma unroll
            for (int q = 0; q < 8; ++q)
                acc[pr][q] = fmaf(wv, rf[cb + q], acc[pr][q]);
        }
        taps<E + 1, RR>(wc, rf, acc);
    }
}

// Per staged row RR: 3x ds_read_b128 (quad-XOR swizzled), convert ONCE to f32, apply taps.
template <int RR>
__device__ __forceinline__ void rows_from(const char* __restrict__ rowbase,
                                          int a0, int a1, int a2, int s0,
                                          const float* __restrict__ wc, float (&acc)[4][8]) {
    if constexpr (RR < 20) {
        constexpr int sflip = ((RR >> 2) & 1) << 4;   // row-parity part of the quad-XOR
        const int s = s0 ^ sflip;                     // s0 = (ty&1)<<4 (runtime, 1 xor/row)
        union { uint4 u[3]; __half h[24]; } R;
        R.u[0] = *reinterpret_cast<const uint4*>(rowbase + RR * ROW_BYTES + (a0 ^ s));
        R.u[1] = *reinterpret_cast<const uint4*>(rowbase + RR * ROW_BYTES + (a1 ^ s));
        R.u[2] = *reinterpret_cast<const uint4*>(rowbase + RR * ROW_BYTES + (a2 ^ s));
        float rf[24];                                  // convert once per row (24 cvt)
#pragma unroll
        for (int i = 0; i < 24; ++i) rf[i] = __half2float(R.h[i]);
        taps<0, RR>(wc, rf, acc);
        rows_from<RR + 1>(rowbase, a0, a1, a2, s0, wc, acc);
    }
}

// pw[ch*57 + e] = sum over branches b (dil d=1,2,4) hitting merged tap e of
//                 s_b * w_b[ch][r/d+2][c/d+2].   pw[171] = combined bias.
__global__ void pack_weights(const float* __restrict__ w1, const float* __restrict__ b1,
                             const float* __restrict__ w2, const float* __restrict__ b2,
                             const float* __restrict__ w3, const float* __restrict__ b3,
                             const float* __restrict__ sa, const float* __restrict__ sb,
                             const float* __restrict__ sc, float* __restrict__ pw) {
    int tid = threadIdx.x;
    float s[3] = {sa[0], sb[0], sc[0]};
    const float* wp[3] = {w1, w2, w3};
    if (tid < 171) {
        int ch = tid / 57;
        int e  = tid % 57;
        int r = kTapR[e];
        int c = kTapC[e];
        float acc = 0.0f;
        for (int b = 0; b < 3; ++b) {
            int d = 1 << b;
            if (r % d == 0 && c % d == 0) {
                int rd = r / d, cd = c / d;
                if (rd >= -2 && rd <= 2 && cd >= -2 && cd <= 2)
                    acc += s[b] * wp[b][ch * 25 + (rd + 2) * 5 + (cd + 2)];
            }
        }
        pw[tid] = acc;
    }
    if (tid == 0) pw[171] = s[0] * b1[0] + s[1] * b2[0] + s[2] * b3[0];
}

__global__ __launch_bounds__(256, 4) void conv_block(const float* __restrict__ x,
                                                     float* __restrict__ out,
                                                     const float* __restrict__ pw) {
    __shared__ char lds[PLANE_BYTES];   // one fp16 channel plane at a time

    const int bt = blockIdx.z;
    const int t  = bt % TT;
    const int h0 = blockIdx.y * TH;
    const int w0 = blockIdx.x * TW;
    const int tid = threadIdx.x;
    const int tx = tid & 15;
    const int ty = tid >> 4;
    const int oc = tx * 8;
    const int orow = ty * 4;

    const int tprev = (t == 0) ? 1 : t - 1;
    const int tnext = (t == TT - 1) ? TT - 2 : t + 1;
    const int bbase = (bt / TT) * TT;
    const size_t fs = (size_t)HH * WW;
    const float* frp = x + (size_t)(bbase + tprev) * fs;
    const float* frc = x + (size_t)bt * fs;
    const float* frn = x + (size_t)(bbase + tnext) * fs;

    const float bias = pw[171];
    float acc[4][8];
#pragma unroll
    for (int p = 0; p < 4; ++p)
#pragma unroll
        for (int q = 0; q < 8; ++q) acc[p][q] = bias;

    // Per-thread read-address components (quad units of 16B; XOR bit 4 = quad LSB)
    const int a0 = (tx + 0) << 4;
    const int a1 = (tx + 1) << 4;
    const int a2 = (tx + 2) << 4;
    const int s0 = (ty & 1) << 4;     // parity of (row>>2) for row = 4ty + RR, RR<4

#pragma unroll 1
    for (int ch = 0; ch < 3; ++ch) {
        const float* src = (ch == 0) ? frp : (ch == 1) ? frc : frn;

        __syncthreads();   // protect plane from previous channel's readers
        // ---- Stage one channel plane: fp32 global -> fp16 LDS, quad-XOR by (row>>2)&1 ----
        for (int k = tid; k < SRODS * 18; k += 256) {
            int row = k / 18;
            int c8  = k - row * 18;
            int gh = reflect_idx(h0 - 8 + row, HH);
            int gb = w0 - 8 + c8 * 8;
            const float* rsrc = src + (size_t)gh * WW;
            float4 v0, v1;
            if (gb >= 0 && gb + 7 < WW) {
                v0 = *reinterpret_cast<const float4*>(rsrc + gb);
                v1 = *reinterpret_cast<const float4*>(rsrc + gb + 4);
            } else {
                v0 = make_float4(rsrc[reflect_idx(gb + 0, WW)], rsrc[reflect_idx(gb + 1, WW)],
                                 rsrc[reflect_idx(gb + 2, WW)], rsrc[reflect_idx(gb + 3, WW)]);
                v1 = make_float4(rsrc[reflect_idx(gb + 4, WW)], rsrc[reflect_idx(gb + 5, WW)],
                                 rsrc[reflect_idx(gb + 6, WW)], rsrc[reflect_idx(gb + 7, WW)]);
            }
            union { __half2 h[4]; uint4 u; } cv;
            cv.h[0] = __floats2half2_rn(v0.x, v0.y);
            cv.h[1] = __floats2half2_rn(v0.z, v0.w);
            cv.h[2] = __floats2half2_rn(v1.x, v1.y);
            cv.h[3] = __floats2half2_rn(v1.z, v1.w);
            int wadr = row * ROW_BYTES + ((c8 << 4) ^ (((row >> 2) & 1) << 4));
            *reinterpret_cast<uint4*>(lds + wadr) = cv.u;
        }
        __syncthreads();

        // ---- Row-streaming: forced-static 20-row x 57-tap expansion ----
        const char* rowbase = lds + orow * ROW_BYTES;
        rows_from<0>(rowbase, a0, a1, a2, s0, pw + ch * 57, acc);
    }

    // ---- Epilogue: tanh + fp32 store ----
    float* dst = out + (size_t)bt * fs + (size_t)h0 * WW + w0;
#pragma unroll
    for (int p = 0; p < 4; ++p) {
#pragma unroll
        for (int q = 0; q < 8; ++q) {
            float v = acc[p][q];
            float e = __expf(2.0f * v);
            acc[p][q] = 1.0f - 2.0f / (e + 1.0f);
        }
        float4 v0 = make_float4(acc[p][0], acc[p][1], acc[p][2], acc[p][3]);
        float4 v1 = make_float4(acc[p][4], acc[p][5], acc[p][6], acc[p][7]);
        float* rowp = dst + (size_t)(orow + p) * WW + oc;
        *reinterpret_cast<float4*>(rowp) = v0;
        *reinterpret_cast<float4*>(rowp + 4) = v1;
    }
}

extern "C" void kernel_launch(void* const* d_in, const int* in_sizes, int n_in,
                              void* d_out, int out_size, void* d_ws, size_t ws_size,
                              hipStream_t stream) {
    const float* x = (const float*)d_in[0];
    float* pw1 = (float*)d_ws;
    float* pw2 = (float*)d_ws + 256;
    float* y   = (float*)((char*)d_ws + 4096);   // intermediate, 64 MB
    float* z   = (float*)d_out;

    pack_weights<<<1, 256, 0, stream>>>((const float*)d_in[1], (const float*)d_in[2],
                                        (const float*)d_in[3], (const float*)d_in[4],
                                        (const float*)d_in[5], (const float*)d_in[6],
                                        (const float*)d_in[7], (const float*)d_in[8],
                                        (const float*)d_in[9], pw1);
    pack_weights<<<1, 256, 0, stream>>>((const float*)d_in[10], (const float*)d_in[11],
                                        (const float*)d_in[12], (const float*)d_in[13],
                                        (const float*)d_in[14], (const float*)d_in[15],
                                        (const float*)d_in[16], (const float*)d_in[17],
                                        (const float*)d_in[18], pw2);

    dim3 grid(WW / TW, HH / TH, BB * TT);
    conv_block<<<grid, 256, 0, stream>>>(x, y, pw1);
    conv_block<<<grid, 256, 0, stream>>>(y, z, pw2);
}

// Round 8
// 249.033 us; speedup vs baseline: 4.3072x; 1.1878x over previous
//
#include <hip/hip_runtime.h>
#include <hip/hip_fp16.h>

// Problem constants
#define BB 4
#define TT 16
#define HH 512
#define WW 512

// Tile: 256 threads = 4 waves; output 64x64. Wave w owns rows 16w..16w+15,
// iterating 4 column strips of 16. One MFMA = 16 rows x 16 cols x one tap-row.
#define BTILE 64
#define ROWB 176                      // plane row stride bytes (88 halfs, 80 used)
#define PROWS 80                      // 64 + 2*8 halo
#define PLANE_BYTES (PROWS * ROWB)    // 14080; 3 planes = 42240 B -> 3 blocks/CU

typedef _Float16 half8 __attribute__((ext_vector_type(8)));
typedef float f32x4 __attribute__((ext_vector_type(4)));

constexpr int kR[9] = {-8, -4, -2, -1, 0, 1, 2, 4, 8};   // merged tap rows

__device__ __forceinline__ int reflect_idx(int q, int n) {
    q = abs(q);
    if (q >= n) q = 2 * n - 2 - q;
    return q;
}

// Build 27 B-fragment matrices (ch x tap-row), 32x16 f16 banded-Toeplitz, stored
// directly in MFMA fragment order: frag[(ch*9+ri)*64 + lane][e], e=0..7,
// B[k][j] with j=lane&15, k=8*(lane>>4)+e, value = merged_w[ch][r][k-8-j] (0 off-band).
// Bias (a*b1+b*b2+c*b3) stored as float at halfs[27*64*8].
__global__ void pack_bfrag(const float* __restrict__ w1, const float* __restrict__ b1,
                           const float* __restrict__ w2, const float* __restrict__ b2,
                           const float* __restrict__ w3, const float* __restrict__ b3,
                           const float* __restrict__ sa, const float* __restrict__ sb,
                           const float* __restrict__ sc_, __half* __restrict__ bfrag) {
    const int tid = threadIdx.x;
    float s[3] = {sa[0], sb[0], sc_[0]};
    const float* wp[3] = {w1, w2, w3};
    for (int idx = tid; idx < 27 * 64; idx += 256) {
        int mat = idx >> 6;
        int lane = idx & 63;
        int ch = mat / 9, ri = mat % 9;
        int r = kR[ri];
        int j = lane & 15, kg = lane >> 4;
        union { __half h[8]; uint4 u; } v;
#pragma unroll
        for (int e = 0; e < 8; ++e) {
            int k = kg * 8 + e;
            int c = k - 8 - j;                 // column offset this (k,j) represents
            float a = 0.f;
            if (c >= -8 && c <= 8) {
                for (int b = 0; b < 3; ++b) {  // merge dilations 1,2,4
                    int d = 1 << b;
                    if (r % d == 0 && c % d == 0) {
                        int rd = r / d, cd = c / d;
                        if (rd >= -2 && rd <= 2 && cd >= -2 && cd <= 2)
                            a += s[b] * wp[b][ch * 25 + (rd + 2) * 5 + (cd + 2)];
                    }
                }
            }
            v.h[e] = __float2half(a);
        }
        *reinterpret_cast<uint4*>(bfrag + idx * 8) = v.u;
    }
    if (tid == 0)
        *reinterpret_cast<float*>(bfrag + 27 * 64 * 8) = s[0] * b1[0] + s[1] * b2[0] + s[2] * b3[0];
}

template <typename InT, typename OutT>
__global__ __launch_bounds__(256, 4) void conv_mfma(const InT* __restrict__ x,
                                                    OutT* __restrict__ out,
                                                    const __half* __restrict__ bfrag) {
    __shared__ char lds[3 * PLANE_BYTES];

    const int bt = blockIdx.z;
    const int t  = bt % TT;
    const int h0 = blockIdx.y * BTILE;
    const int w0 = blockIdx.x * BTILE;
    const int tid = threadIdx.x;
    const int lane = tid & 63;
    const int wv = tid >> 6;                  // wave id 0..3

    const int tprev = (t == 0) ? 1 : t - 1;
    const int tnext = (t == TT - 1) ? TT - 2 : t + 1;
    const int bbase = (bt / TT) * TT;
    const size_t fs = (size_t)HH * WW;
    const InT* f0 = x + (size_t)(bbase + tprev) * fs;
    const InT* f1 = x + (size_t)bt * fs;
    const InT* f2 = x + (size_t)(bbase + tnext) * fs;

    // ---- Stage 3 channel planes (rows h0-8..h0+71, cols w0-8..w0+71) as f16 ----
    for (int k2 = tid; k2 < 3 * 800; k2 += 256) {
        int ch  = k2 / 800;
        int rem = k2 - ch * 800;
        int row = rem / 10;
        int c8  = rem - row * 10;
        const InT* src = (ch == 0) ? f0 : (ch == 1) ? f1 : f2;
        int gh = reflect_idx(h0 - 8 + row, HH);
        int gb = w0 - 8 + c8 * 8;
        const InT* rp = src + (size_t)gh * WW;
        union { __half h[8]; uint4 u; } cv;
        if (gb >= 0 && gb + 7 < WW) {
            if constexpr (sizeof(InT) == 4) {
                const float4 v0 = *reinterpret_cast<const float4*>((const float*)rp + gb);
                const float4 v1 = *reinterpret_cast<const float4*>((const float*)rp + gb + 4);
                cv.h[0] = __float2half(v0.x); cv.h[1] = __float2half(v0.y);
                cv.h[2] = __float2half(v0.z); cv.h[3] = __float2half(v0.w);
                cv.h[4] = __float2half(v1.x); cv.h[5] = __float2half(v1.y);
                cv.h[6] = __float2half(v1.z); cv.h[7] = __float2half(v1.w);
            } else {
                cv.u = *reinterpret_cast<const uint4*>((const __half*)rp + gb);
            }
        } else {
#pragma unroll
            for (int e = 0; e < 8; ++e) {
                int g = reflect_idx(gb + e, WW);
                if constexpr (sizeof(InT) == 4) cv.h[e] = __float2half(((const float*)rp)[g]);
                else                            cv.h[e] = ((const __half*)rp)[g];
            }
        }
        *reinterpret_cast<uint4*>(lds + ch * PLANE_BYTES + row * ROWB + c8 * 16) = cv.u;
    }
    __syncthreads();   // single barrier; LDS read-only afterwards

    const float bias = *reinterpret_cast<const float*>(bfrag + 27 * 64 * 8);
    f32x4 acc0 = {bias, bias, bias, bias};
    f32x4 acc1 = acc0, acc2 = acc0, acc3 = acc0;

    const int i16 = lane & 15;                // A row within strip / C col
    const int kg  = lane >> 4;                // k-group (8 consecutive k)
    // A[i,k] = plane[16w + i + r + 8][16sc + k]; rebase at r=-8 so offsets are literals
    const char* aB0 = lds + (16 * wv + i16) * ROWB + kg * 16;

#pragma unroll 1
    for (int ch = 0; ch < 3; ++ch) {
        const char* aB = aB0 + ch * PLANE_BYTES;
        const __half* bp = bfrag + (size_t)ch * 9 * 512 + lane * 8;
        half8 bf[9];
#pragma unroll
        for (int ri = 0; ri < 9; ++ri)
            bf[ri] = *reinterpret_cast<const half8*>(bp + ri * 512);
#pragma unroll
        for (int ri = 0; ri < 9; ++ri) {
            const char* ar = aB + (kR[ri] + 8) * ROWB;   // literal offset per ri
            half8 a0 = *reinterpret_cast<const half8*>(ar);
            half8 a1 = *reinterpret_cast<const half8*>(ar + 32);
            half8 a2 = *reinterpret_cast<const half8*>(ar + 64);
            half8 a3 = *reinterpret_cast<const half8*>(ar + 96);
            acc0 = __builtin_amdgcn_mfma_f32_16x16x32_f16(a0, bf[ri], acc0, 0, 0, 0);
            acc1 = __builtin_amdgcn_mfma_f32_16x16x32_f16(a1, bf[ri], acc1, 0, 0, 0);
            acc2 = __builtin_amdgcn_mfma_f32_16x16x32_f16(a2, bf[ri], acc2, 0, 0, 0);
            acc3 = __builtin_amdgcn_mfma_f32_16x16x32_f16(a3, bf[ri], acc3, 0, 0, 0);
        }
    }

    // ---- Epilogue: C layout col=lane&15, row=(lane>>4)*4+reg (m89-verified) ----
    OutT* dst = out + (size_t)bt * fs + (size_t)(h0 + 16 * wv + kg * 4) * WW + (w0 + i16);
#pragma unroll
    for (int sc = 0; sc < 4; ++sc) {
        f32x4 a = (sc == 0) ? acc0 : (sc == 1) ? acc1 : (sc == 2) ? acc2 : acc3;
#pragma unroll
        for (int v2 = 0; v2 < 4; ++v2) {
            float z = a[v2];
            float e = __expf(2.0f * z);
            z = 1.0f - 2.0f / (e + 1.0f);                // tanh
            if constexpr (sizeof(OutT) == 2)
                dst[(size_t)v2 * WW + sc * 16] = __float2half(z);
            else
                dst[(size_t)v2 * WW + sc * 16] = z;
        }
    }
}

extern "C" void kernel_launch(void* const* d_in, const int* in_sizes, int n_in,
                              void* d_out, int out_size, void* d_ws, size_t ws_size,
                              hipStream_t stream) {
    const float* x = (const float*)d_in[0];
    char* ws = (char*)d_ws;
    __half* y   = (__half*)ws;                              // fp16 intermediate, 32 MB
    __half* bf1 = (__half*)(ws + 33554432);                 // 27652 B
    __half* bf2 = (__half*)(ws + 33554432 + 32768);         // total ~33.6 MB (< proven ws)
    float* z = (float*)d_out;

    pack_bfrag<<<1, 256, 0, stream>>>((const float*)d_in[1], (const float*)d_in[2],
                                      (const float*)d_in[3], (const float*)d_in[4],
                                      (const float*)d_in[5], (const float*)d_in[6],
                                      (const float*)d_in[7], (const float*)d_in[8],
                                      (const float*)d_in[9], bf1);
    pack_bfrag<<<1, 256, 0, stream>>>((const float*)d_in[10], (const float*)d_in[11],
                                      (const float*)d_in[12], (const float*)d_in[13],
                                      (const float*)d_in[14], (const float*)d_in[15],
                                      (const float*)d_in[16], (const float*)d_in[17],
                                      (const float*)d_in[18], bf2);

    dim3 grid(WW / BTILE, HH / BTILE, BB * TT);   // 8 x 8 x 64
    conv_mfma<float, __half><<<grid, 256, 0, stream>>>(x, y, bf1);
    conv_mfma<__half, float><<<grid, 256, 0, stream>>>(y, z, bf2);
}

// Round 9
// 175.108 us; speedup vs baseline: 6.1256x; 1.4222x over previous
//
#include <hip/hip_runtime.h>
#include <hip/hip_fp16.h>

// Problem constants
#define BB 4
#define TT 16
#define HH 512
#define WW 512
#define SP 528                        // padded row stride (halfs) for the f16 inter-pass buffer

// Tile: 256 threads = 4 waves; output 64x64. Wave w owns rows 16w..16w+15 x 64 cols.
#define BTILE 64
#define ROWB 160                      // LDS plane row stride bytes (80 halfs, exact fit)
#define PROWS 80                      // 64 + 2*8 halo
#define PLANE_STRIDE 13312            // 13 x 1024B chunks (12800 used) - DMA-chunk aligned
#define LDS_BYTES (3 * PLANE_STRIDE)  // 39936 B -> 4 blocks/CU

typedef _Float16 half8 __attribute__((ext_vector_type(8)));
typedef float f32x4 __attribute__((ext_vector_type(4)));

constexpr int kR[9] = {-8, -4, -2, -1, 0, 1, 2, 4, 8};   // merged tap rows

__device__ __forceinline__ int reflect_idx(int q, int n) {
    q = abs(q);
    if (q >= n) q = 2 * n - 2 - q;
    return q;
}

__device__ __forceinline__ void async_cp16(const __half* g, char* l) {
#if __has_builtin(__builtin_amdgcn_global_load_lds)
    __builtin_amdgcn_global_load_lds(
        (const __attribute__((address_space(1))) unsigned int*)g,
        (__attribute__((address_space(3))) unsigned int*)l, 16, 0, 0);
#else
    *reinterpret_cast<uint4*>(l) = *reinterpret_cast<const uint4*>(g);
#endif
}

// 27 B-fragment matrices (ch x tap-row), 32x16 f16 banded-Toeplitz in MFMA fragment order:
// frag[(ch*9+ri)*64 + lane][e], B[k][j], j=lane&15, k=8*(lane>>4)+e, val=merged_w[ch][r][k-8-j].
// Combined bias stored as float at halfs[27*64*8].
__global__ void pack_bfrag(const float* __restrict__ w1, const float* __restrict__ b1,
                           const float* __restrict__ w2, const float* __restrict__ b2,
                           const float* __restrict__ w3, const float* __restrict__ b3,
                           const float* __restrict__ sa, const float* __restrict__ sb,
                           const float* __restrict__ sc_, __half* __restrict__ bfrag) {
    const int tid = threadIdx.x;
    float s[3] = {sa[0], sb[0], sc_[0]};
    const float* wp[3] = {w1, w2, w3};
    for (int idx = tid; idx < 27 * 64; idx += 256) {
        int mat = idx >> 6;
        int lane = idx & 63;
        int ch = mat / 9, ri = mat % 9;
        int r = kR[ri];
        int j = lane & 15, kg = lane >> 4;
        union { __half h[8]; uint4 u; } v;
#pragma unroll
        for (int e = 0; e < 8; ++e) {
            int k = kg * 8 + e;
            int c = k - 8 - j;
            float a = 0.f;
            if (c >= -8 && c <= 8) {
                for (int b = 0; b < 3; ++b) {
                    int d = 1 << b;
                    if (r % d == 0 && c % d == 0) {
                        int rd = r / d, cd = c / d;
                        if (rd >= -2 && rd <= 2 && cd >= -2 && cd <= 2)
                            a += s[b] * wp[b][ch * 25 + (rd + 2) * 5 + (cd + 2)];
                    }
                }
            }
            v.h[e] = __float2half(a);
        }
        *reinterpret_cast<uint4*>(bfrag + idx * 8) = v.u;
    }
    if (tid == 0)
        *reinterpret_cast<float*>(bfrag + 27 * 64 * 8) = s[0] * b1[0] + s[1] * b2[0] + s[2] * b3[0];
}

// PASS 1: in = f32 x (unpadded), out = f16 ypad (stride SP, reflect-padded cols)
// PASS 2: in = f16 ypad,         out = f32 z   (unpadded)
template <int PASS>
__global__ __launch_bounds__(256, 4) void conv_mfma(const void* __restrict__ xin,
                                                    void* __restrict__ outp,
                                                    const __half* __restrict__ bfrag) {
    __shared__ char lds[LDS_BYTES];

    const int bt = blockIdx.z;
    const int t  = bt % TT;
    const int h0 = blockIdx.y * BTILE;
    const int w0 = blockIdx.x * BTILE;
    const int tid = threadIdx.x;
    const int lane = tid & 63;
    const int wv = tid >> 6;

    const int tprev = (t == 0) ? 1 : t - 1;
    const int tnext = (t == TT - 1) ? TT - 2 : t + 1;
    const int bbase = (bt / TT) * TT;

    if constexpr (PASS == 1) {
        // ---- manual staging: f32 global -> f16 LDS, full reflect ----
        const float* x = (const float*)xin;
        const size_t fs = (size_t)HH * WW;
        const float* f0 = x + (size_t)(bbase + tprev) * fs;
        const float* f1 = x + (size_t)bt * fs;
        const float* f2 = x + (size_t)(bbase + tnext) * fs;
        for (int k2 = tid; k2 < 2400; k2 += 256) {
            int ch  = k2 / 800;
            int rem = k2 - ch * 800;
            int row = rem / 10;
            int c8  = rem - row * 10;
            const float* src = (ch == 0) ? f0 : (ch == 1) ? f1 : f2;
            int gh = reflect_idx(h0 - 8 + row, HH);
            int gb = w0 - 8 + c8 * 8;
            const float* rp = src + (size_t)gh * WW;
            union { __half h[8]; uint4 u; } cv;
            if (gb >= 0 && gb + 7 < WW) {
                const float4 v0 = *reinterpret_cast<const float4*>(rp + gb);
                const float4 v1 = *reinterpret_cast<const float4*>(rp + gb + 4);
                cv.h[0] = __float2half(v0.x); cv.h[1] = __float2half(v0.y);
                cv.h[2] = __float2half(v0.z); cv.h[3] = __float2half(v0.w);
                cv.h[4] = __float2half(v1.x); cv.h[5] = __float2half(v1.y);
                cv.h[6] = __float2half(v1.z); cv.h[7] = __float2half(v1.w);
            } else {
#pragma unroll
                for (int e = 0; e < 8; ++e)
                    cv.h[e] = __float2half(rp[reflect_idx(gb + e, WW)]);
            }
            *reinterpret_cast<uint4*>(lds + ch * PLANE_STRIDE + row * ROWB + c8 * 16) = cv.u;
        }
        __syncthreads();
    } else {
        // ---- DMA staging: f16 padded global -> LDS via global_load_lds ----
        const __half* y = (const __half*)xin;
        const size_t fsP = (size_t)HH * SP;
        const __half* f0 = y + (size_t)(bbase + tprev) * fsP;
        const __half* f1 = y + (size_t)bt * fsP;
        const __half* f2 = y + (size_t)(bbase + tnext) * fsP;
        for (int c = wv; c < 39; c += 4) {       // 13 chunks x 3 planes, wave-uniform
            int plane = c / 13;
            int sub   = c - plane * 13;
            const __half* srcf = (plane == 0) ? f0 : (plane == 1) ? f1 : f2;
            int byt = sub * 1024 + lane * 16;
            if (byt < PROWS * ROWB) {            // tail lanes of chunk 12 masked
                int row  = byt / ROWB;
                int colh = (byt - row * ROWB) >> 1;
                int gh = reflect_idx(h0 - 8 + row, HH);
                const __half* g = srcf + (size_t)gh * SP + (w0 + colh);  // pad +8 == halo -8
                async_cp16(g, lds + plane * PLANE_STRIDE + byt);
            }
        }
        asm volatile("s_waitcnt vmcnt(0)" ::: "memory");
        __syncthreads();
    }

    // ---- MFMA compute: 3 ch x 9 tap-rows x 4 col-strips (proven in round 8) ----
    const float bias = *reinterpret_cast<const float*>(bfrag + 27 * 64 * 8);
    f32x4 acc0 = {bias, bias, bias, bias};
    f32x4 acc1 = acc0, acc2 = acc0, acc3 = acc0;

    const int i16 = lane & 15;
    const int kg  = lane >> 4;
    const char* aB0 = lds + (16 * wv + i16) * ROWB + kg * 16;

#pragma unroll
    for (int ch = 0; ch < 3; ++ch) {
        const char* aB = aB0 + ch * PLANE_STRIDE;
        const __half* bp = bfrag + (size_t)ch * 9 * 512 + lane * 8;
        half8 bf[9];
#pragma unroll
        for (int ri = 0; ri < 9; ++ri)
            bf[ri] = *reinterpret_cast<const half8*>(bp + ri * 512);
#pragma unroll
        for (int ri = 0; ri < 9; ++ri) {
            const char* ar = aB + (kR[ri] + 8) * ROWB;
            half8 a0 = *reinterpret_cast<const half8*>(ar);
            half8 a1 = *reinterpret_cast<const half8*>(ar + 32);
            half8 a2 = *reinterpret_cast<const half8*>(ar + 64);
            half8 a3 = *reinterpret_cast<const half8*>(ar + 96);
            __builtin_amdgcn_s_setprio(1);
            acc0 = __builtin_amdgcn_mfma_f32_16x16x32_f16(a0, bf[ri], acc0, 0, 0, 0);
            acc1 = __builtin_amdgcn_mfma_f32_16x16x32_f16(a1, bf[ri], acc1, 0, 0, 0);
            acc2 = __builtin_amdgcn_mfma_f32_16x16x32_f16(a2, bf[ri], acc2, 0, 0, 0);
            acc3 = __builtin_amdgcn_mfma_f32_16x16x32_f16(a3, bf[ri], acc3, 0, 0, 0);
            __builtin_amdgcn_s_setprio(0);
        }
    }

    // ---- Epilogue: tanh; C layout col=lane&15, row=(lane>>4)*4+reg ----
    if constexpr (PASS == 1) {
        __half* yp = (__half*)outp + (size_t)bt * HH * SP;
#pragma unroll
        for (int sc = 0; sc < 4; ++sc) {
            f32x4 a = (sc == 0) ? acc0 : (sc == 1) ? acc1 : (sc == 2) ? acc2 : acc3;
            const int wcol = w0 + sc * 16 + i16;
#pragma unroll
            for (int v2 = 0; v2 < 4; ++v2) {
                float z = a[v2];
                float e = __expf(2.0f * z);
                z = 1.0f - 2.0f / (e + 1.0f);
                __half hz = __float2half(z);
                __half* rb = yp + (size_t)(h0 + 16 * wv + kg * 4 + v2) * SP;
                rb[8 + wcol] = hz;
                if (wcol >= 1 && wcol <= 8)          rb[8 - wcol] = hz;       // left mirror
                else if (wcol >= 503 && wcol <= 510) rb[1030 - wcol] = hz;    // right mirror
            }
        }
    } else {
        float* dst = (float*)outp + (size_t)bt * HH * WW
                   + (size_t)(h0 + 16 * wv + kg * 4) * WW + (w0 + i16);
#pragma unroll
        for (int sc = 0; sc < 4; ++sc) {
            f32x4 a = (sc == 0) ? acc0 : (sc == 1) ? acc1 : (sc == 2) ? acc2 : acc3;
#pragma unroll
            for (int v2 = 0; v2 < 4; ++v2) {
                float z = a[v2];
                float e = __expf(2.0f * z);
                dst[(size_t)v2 * WW + sc * 16] = 1.0f - 2.0f / (e + 1.0f);
            }
        }
    }
}

extern "C" void kernel_launch(void* const* d_in, const int* in_sizes, int n_in,
                              void* d_out, int out_size, void* d_ws, size_t ws_size,
                              hipStream_t stream) {
    const float* x = (const float*)d_in[0];
    char* ws = (char*)d_ws;
    __half* bf1  = (__half*)ws;                        // 27.7 KB
    __half* bf2  = (__half*)(ws + 32768);              // 27.7 KB
    __half* ypad = (__half*)(ws + 65536);              // 64 x 512 x 528 f16 = 34.6 MB

    pack_bfrag<<<1, 256, 0, stream>>>((const float*)d_in[1], (const float*)d_in[2],
                                      (const float*)d_in[3], (const float*)d_in[4],
                                      (const float*)d_in[5], (const float*)d_in[6],
                                      (const float*)d_in[7], (const float*)d_in[8],
                                      (const float*)d_in[9], bf1);
    pack_bfrag<<<1, 256, 0, stream>>>((const float*)d_in[10], (const float*)d_in[11],
                                      (const float*)d_in[12], (const float*)d_in[13],
                                      (const float*)d_in[14], (const float*)d_in[15],
                                      (const float*)d_in[16], (const float*)d_in[17],
                                      (const float*)d_in[18], bf2);

    dim3 grid(WW / BTILE, HH / BTILE, BB * TT);   // 8 x 8 x 64
    conv_mfma<1><<<grid, 256, 0, stream>>>(x, ypad, bf1);
    conv_mfma<2><<<grid, 256, 0, stream>>>(ypad, d_out, bf2);
}